// Round 1
// baseline (278.997 us; speedup 1.0000x reference)
//
#include <hip/hip_runtime.h>

constexpr int N_NODES = 100000;
constexpr int N_FEAT  = 512;    // 128 float4 per row
constexpr int N_EDGES = 1600000;

// ws layout (float offsets):
//   [0, 512)          W0 (column 0 of w1@w2)
//   [512, 1024)       W1 (column 1)
//   [1024, 1026)      c  (b1@w2 + b2)
//   [1056, 101056)    deg (int) -> dinv (float), in place
//   [101056, 301056)  gs = (x@W) * dinv[row],  [N,2]
// total ~1.18 MB
constexpr int WS_W0   = 0;
constexpr int WS_W1   = 512;
constexpr int WS_C    = 1024;
constexpr int WS_DINV = 1056;
constexpr int WS_GS   = 101056;

// ---- kernel 1: W = w1 @ w2 (512x128 @ 128x2), c = b1@w2 + b2 ----
__global__ void k_w(const float* __restrict__ w1, const float* __restrict__ w2,
                    const float* __restrict__ b1, const float* __restrict__ b2,
                    float* __restrict__ ws) {
    int k = blockIdx.x * blockDim.x + threadIdx.x;
    if (k >= N_FEAT) return;
    float a0 = 0.f, a1 = 0.f;
    for (int m = 0; m < 128; ++m) {
        float w = w1[k * 128 + m];
        a0 += w * w2[m * 2 + 0];
        a1 += w * w2[m * 2 + 1];
    }
    ws[WS_W0 + k] = a0;
    ws[WS_W1 + k] = a1;
    if (k < 2) {
        float s = b2[k];
        for (int m = 0; m < 128; ++m) s += b1[m] * w2[m * 2 + k];
        ws[WS_C + k] = s;
    }
}

// ---- kernel 2: deg[i] = 1 (self-loop) ----
__global__ void k_deg_init(int* __restrict__ deg) {
    int i = blockIdx.x * blockDim.x + threadIdx.x;
    if (i < N_NODES) deg[i] = 1;
}

// ---- kernel 3: histogram over dst ----
__global__ void k_deg(const int* __restrict__ dst, int* __restrict__ deg) {
    int e = blockIdx.x * blockDim.x + threadIdx.x;
    if (e < N_EDGES) atomicAdd(&deg[dst[e]], 1);
}

// ---- kernel 4: dinv = rsqrt(deg), in place ----
__global__ void k_dinv(float* __restrict__ dinv_io) {
    int i = blockIdx.x * blockDim.x + threadIdx.x;
    if (i >= N_NODES) return;
    int d = reinterpret_cast<const int*>(dinv_io)[i];
    dinv_io[i] = rsqrtf((float)d);
}

// ---- kernel 5: per row: g = x_row @ W; gs = g*dinv; out = gs*dinv + c ----
// one wave per row; W fragment lives in 16 registers per lane; coalesced float4.
__global__ __launch_bounds__(256) void k_rowdot(
    const float* __restrict__ x, const float* __restrict__ ws,
    float* __restrict__ gs, float* __restrict__ out) {
    const float4* W0q = reinterpret_cast<const float4*>(ws + WS_W0);
    const float4* W1q = reinterpret_cast<const float4*>(ws + WS_W1);
    const float*  c   = ws + WS_C;
    const float*  dinv = ws + WS_DINV;
    int lane = threadIdx.x & 63;
    int wave = threadIdx.x >> 6;

    float4 w0a = W0q[lane], w0b = W0q[64 + lane];
    float4 w1a = W1q[lane], w1b = W1q[64 + lane];
    float  c0 = c[0], c1 = c[1];

    int wave_id = blockIdx.x * 4 + wave;
    int nwaves  = gridDim.x * 4;
    for (int row = wave_id; row < N_NODES; row += nwaves) {
        const float4* xq = reinterpret_cast<const float4*>(x + (size_t)row * N_FEAT);
        float4 xa = xq[lane], xb = xq[64 + lane];
        float a0 = xa.x*w0a.x + xa.y*w0a.y + xa.z*w0a.z + xa.w*w0a.w
                 + xb.x*w0b.x + xb.y*w0b.y + xb.z*w0b.z + xb.w*w0b.w;
        float a1 = xa.x*w1a.x + xa.y*w1a.y + xa.z*w1a.z + xa.w*w1a.w
                 + xb.x*w1b.x + xb.y*w1b.y + xb.z*w1b.z + xb.w*w1b.w;
        #pragma unroll
        for (int off = 32; off >= 1; off >>= 1) {
            a0 += __shfl_down(a0, off);
            a1 += __shfl_down(a1, off);
        }
        if (lane == 0) {
            float di = dinv[row];
            float g0 = a0 * di, g1 = a1 * di;
            gs[row * 2 + 0] = g0;
            gs[row * 2 + 1] = g1;
            out[row * 2 + 0] = g0 * di + c0;   // self-loop term + bias
            out[row * 2 + 1] = g1 * di + c1;
        }
    }
}

// ---- kernel 6: out[dst] += gs[src] * dinv[dst] over edges ----
__global__ void k_scatter(const int* __restrict__ src, const int* __restrict__ dst,
                          const float* __restrict__ gs, const float* __restrict__ dinv,
                          float* __restrict__ out) {
    int e = blockIdx.x * blockDim.x + threadIdx.x;
    if (e >= N_EDGES) return;
    int s = src[e], d = dst[e];
    float nd = dinv[d];
    float2 g = reinterpret_cast<const float2*>(gs)[s];
    atomicAdd(&out[d * 2 + 0], g.x * nd);
    atomicAdd(&out[d * 2 + 1], g.y * nd);
}

extern "C" void kernel_launch(void* const* d_in, const int* in_sizes, int n_in,
                              void* d_out, int out_size, void* d_ws, size_t ws_size,
                              hipStream_t stream) {
    const float* x  = (const float*)d_in[0];
    const float* w1 = (const float*)d_in[1];
    const float* b1 = (const float*)d_in[2];
    const float* w2 = (const float*)d_in[3];
    const float* b2 = (const float*)d_in[4];
    const int*   ei = (const int*)d_in[5];   // [2, E]: src row then dst row
    float* out = (float*)d_out;
    float* ws  = (float*)d_ws;

    int* deg = (int*)(ws + WS_DINV);

    k_w<<<(N_FEAT + 255) / 256, 256, 0, stream>>>(w1, w2, b1, b2, ws);
    k_deg_init<<<(N_NODES + 255) / 256, 256, 0, stream>>>(deg);
    k_deg<<<(N_EDGES + 255) / 256, 256, 0, stream>>>(ei + N_EDGES, deg);
    k_dinv<<<(N_NODES + 255) / 256, 256, 0, stream>>>(ws + WS_DINV);
    k_rowdot<<<2048, 256, 0, stream>>>(x, ws, ws + WS_GS, out);
    k_scatter<<<(N_EDGES + 255) / 256, 256, 0, stream>>>(
        ei, ei + N_EDGES, ws + WS_GS, ws + WS_DINV, out);
}

// Round 2
// 193.315 us; speedup vs baseline: 1.4432x; 1.4432x over previous
//
#include <hip/hip_runtime.h>

constexpr int N_NODES = 100000;
constexpr int N_FEAT  = 512;    // 128 float4 per row
constexpr int N_EDGES = 1600000;

// fixed-point packing for the 64-bit scatter atomic
constexpr float FXS = 1048576.0f;  // 2^20 scale
constexpr float FXB = 32.0f;       // positivity bias; FXB*FXS = 2^25 (exact)

// ---- kernel 1: W = w1 @ w2 (512x128 @ 128x2), c = b1@w2 + b2 ----
__global__ void k_w(const float* __restrict__ w1, const float* __restrict__ w2,
                    const float* __restrict__ b1, const float* __restrict__ b2,
                    float* __restrict__ W, float* __restrict__ cvec) {
    int k = blockIdx.x * blockDim.x + threadIdx.x;
    if (k >= N_FEAT) return;
    float a0 = 0.f, a1 = 0.f;
    for (int m = 0; m < 128; ++m) {
        float w = w1[k * 128 + m];
        a0 += w * w2[m * 2 + 0];
        a1 += w * w2[m * 2 + 1];
    }
    W[k] = a0;
    W[512 + k] = a1;
    if (k < 2) {
        float s = b2[k];
        for (int m = 0; m < 128; ++m) s += b1[m] * w2[m * 2 + k];
        cvec[k] = s;
    }
}

// ---- kernel 2: deg[i] = 1 (self-loop), zero u64 accumulator ----
__global__ void k_init(int* __restrict__ deg, unsigned long long* __restrict__ acc) {
    int i = blockIdx.x * blockDim.x + threadIdx.x;
    if (i < N_NODES) {
        deg[i] = 1;
        if (acc) acc[i] = 0ull;
    }
}

// ---- kernel 3: histogram over dst ----
__global__ void k_deg(const int* __restrict__ dst, int* __restrict__ deg) {
    int e = blockIdx.x * blockDim.x + threadIdx.x;
    if (e < N_EDGES) atomicAdd(&deg[dst[e]], 1);
}

// ---- kernel 4: dinv = rsqrt(deg) (may alias deg for in-place) ----
__global__ void k_dinv(const int* __restrict__ deg, float* __restrict__ dinv) {
    int i = blockIdx.x * blockDim.x + threadIdx.x;
    if (i < N_NODES) dinv[i] = rsqrtf((float)deg[i]);
}

// ---- kernel 5: per row: g = x_row @ W; gs = g*dinv[row]; optionally out=gs*dinv+c
__global__ __launch_bounds__(256) void k_rowdot(
    const float* __restrict__ x, const float* __restrict__ W,
    const float* __restrict__ cvec, const float* __restrict__ dinv,
    float* __restrict__ gs, float* __restrict__ out, int write_out) {
    const float4* W0q = reinterpret_cast<const float4*>(W);
    const float4* W1q = reinterpret_cast<const float4*>(W + 512);
    int lane = threadIdx.x & 63;
    int wave = threadIdx.x >> 6;

    float4 w0a = W0q[lane], w0b = W0q[64 + lane];
    float4 w1a = W1q[lane], w1b = W1q[64 + lane];

    int wave_id = blockIdx.x * 4 + wave;
    int nwaves  = gridDim.x * 4;
    for (int row = wave_id; row < N_NODES; row += nwaves) {
        const float4* xq = reinterpret_cast<const float4*>(x + (size_t)row * N_FEAT);
        float4 xa = xq[lane], xb = xq[64 + lane];
        float a0 = xa.x*w0a.x + xa.y*w0a.y + xa.z*w0a.z + xa.w*w0a.w
                 + xb.x*w0b.x + xb.y*w0b.y + xb.z*w0b.z + xb.w*w0b.w;
        float a1 = xa.x*w1a.x + xa.y*w1a.y + xa.z*w1a.z + xa.w*w1a.w
                 + xb.x*w1b.x + xb.y*w1b.y + xb.z*w1b.z + xb.w*w1b.w;
        #pragma unroll
        for (int off = 32; off >= 1; off >>= 1) {
            a0 += __shfl_down(a0, off);
            a1 += __shfl_down(a1, off);
        }
        if (lane == 0) {
            float di = dinv[row];
            float g0 = a0 * di, g1 = a1 * di;
            gs[row * 2 + 0] = g0;
            gs[row * 2 + 1] = g1;
            if (write_out) {
                out[row * 2 + 0] = g0 * di + cvec[0];
                out[row * 2 + 1] = g1 * di + cvec[1];
            }
        }
    }
}

// ---- kernel 6a (fast path): one u64 atomic per edge, biased fixed point ----
// acc[d] += pack( rn((gs0[s]+FXB)*FXS), rn((gs1[s]+FXB)*FXS) )
__global__ void k_scatter64(const int* __restrict__ src, const int* __restrict__ dst,
                            const float* __restrict__ gs,
                            unsigned long long* __restrict__ acc) {
    int e = blockIdx.x * blockDim.x + threadIdx.x;
    if (e >= N_EDGES) return;
    int s = src[e], d = dst[e];
    float2 g = reinterpret_cast<const float2*>(gs)[s];
    unsigned int lo = (unsigned int)__float2int_rn((g.x + FXB) * FXS);
    unsigned int hi = (unsigned int)__float2int_rn((g.y + FXB) * FXS);
    atomicAdd(&acc[d], ((unsigned long long)hi << 32) | (unsigned long long)lo);
}

// ---- kernel 7 (fast path): decode, remove bias, add self-loop term + bias ----
__global__ void k_final(const unsigned long long* __restrict__ acc,
                        const int* __restrict__ deg, const float* __restrict__ dinv,
                        const float* __restrict__ gs, const float* __restrict__ cvec,
                        float* __restrict__ out) {
    int i = blockIdx.x * blockDim.x + threadIdx.x;
    if (i >= N_NODES) return;
    unsigned long long a = acc[i];
    long long lo = (long long)(a & 0xFFFFFFFFull);
    long long hi = (long long)(a >> 32);
    long long cnt = (long long)(deg[i] - 1);                 // real in-edges
    long long bias = cnt * (long long)(int)(FXB * FXS);      // exact: cnt * 2^25
    float s0 = (float)(lo - bias) * (1.0f / FXS);
    float s1 = (float)(hi - bias) * (1.0f / FXS);
    float di = dinv[i];
    float2 g = reinterpret_cast<const float2*>(gs)[i];
    out[i * 2 + 0] = di * (s0 + g.x) + cvec[0];
    out[i * 2 + 1] = di * (s1 + g.y) + cvec[1];
}

// ---- kernel 6b (fallback path): two fp32 atomics per edge ----
__global__ void k_scatter(const int* __restrict__ src, const int* __restrict__ dst,
                          const float* __restrict__ gs, const float* __restrict__ dinv,
                          float* __restrict__ out) {
    int e = blockIdx.x * blockDim.x + threadIdx.x;
    if (e >= N_EDGES) return;
    int s = src[e], d = dst[e];
    float nd = dinv[d];
    float2 g = reinterpret_cast<const float2*>(gs)[s];
    atomicAdd(&out[d * 2 + 0], g.x * nd);
    atomicAdd(&out[d * 2 + 1], g.y * nd);
}

extern "C" void kernel_launch(void* const* d_in, const int* in_sizes, int n_in,
                              void* d_out, int out_size, void* d_ws, size_t ws_size,
                              hipStream_t stream) {
    const float* x  = (const float*)d_in[0];
    const float* w1 = (const float*)d_in[1];
    const float* b1 = (const float*)d_in[2];
    const float* w2 = (const float*)d_in[3];
    const float* b2 = (const float*)d_in[4];
    const int*   ei = (const int*)d_in[5];   // [2, E]: src row then dst row
    const int* e_src = ei;
    const int* e_dst = ei + N_EDGES;
    float* out = (float*)d_out;
    float* ws  = (float*)d_ws;

    // ws layout (float offsets)
    //   [0,512)      W0   [512,1024) W1   [1024,1026) c  (pad to 1056)
    //   [1056,      +100000) deg (int)
    //   [101056,    +100000) dinv (float)
    //   [201056,    +200000) gs [N,2]
    //   [401056,    +200000) acc (u64[N], 8B-aligned: 401056*4 % 8 == 0)
    float* W    = ws;
    float* cvec = ws + 1024;
    int*   deg  = (int*)(ws + 1056);
    float* dinv = ws + 101056;
    float* gs   = ws + 201056;
    unsigned long long* acc = (unsigned long long*)(ws + 401056);

    const size_t need_fast = (size_t)(401056 + 200000) * 4;
    bool fast = ws_size >= need_fast;

    constexpr int EB = (N_EDGES + 255) / 256;
    constexpr int NB = (N_NODES + 255) / 256;

    if (fast) {
        k_w<<<2, 256, 0, stream>>>(w1, w2, b1, b2, W, cvec);
        k_init<<<NB, 256, 0, stream>>>(deg, acc);
        k_deg<<<EB, 256, 0, stream>>>(e_dst, deg);
        k_dinv<<<NB, 256, 0, stream>>>(deg, dinv);
        k_rowdot<<<2048, 256, 0, stream>>>(x, W, cvec, dinv, gs, out, 0);
        k_scatter64<<<EB, 256, 0, stream>>>(e_src, e_dst, gs, acc);
        k_final<<<NB, 256, 0, stream>>>(acc, deg, dinv, gs, cvec, out);
    } else {
        // round-1 layout: deg/dinv in place, no acc
        int*   deg2  = (int*)(ws + 1056);
        float* dinv2 = ws + 1056;
        float* gs2   = ws + 101056;
        k_w<<<2, 256, 0, stream>>>(w1, w2, b1, b2, W, cvec);
        k_init<<<NB, 256, 0, stream>>>(deg2, nullptr);
        k_deg<<<EB, 256, 0, stream>>>(e_dst, deg2);
        k_dinv<<<NB, 256, 0, stream>>>(deg2, dinv2);
        k_rowdot<<<2048, 256, 0, stream>>>(x, W, cvec, dinv2, gs2, out, 1);
        k_scatter<<<EB, 256, 0, stream>>>(e_src, e_dst, gs2, dinv2, out);
    }
}

// Round 4
// 164.047 us; speedup vs baseline: 1.7007x; 1.1784x over previous
//
#include <hip/hip_runtime.h>

constexpr int N_NODES = 100000;
constexpr int N_FEAT  = 512;    // 128 float4 per row
constexpr int N_EDGES = 1600000;

// fixed-point packing for the 64-bit scatter atomic
constexpr float FXS = 1048576.0f;  // 2^20 scale
constexpr float FXB = 32.0f;       // positivity bias; FXB*FXS = 2^25 (exact)

// native clang vector type (required by __builtin_nontemporal_load)
typedef float vfloat4 __attribute__((ext_vector_type(4)));

// ws layout (float offsets)
//   [0,1024)           W (two 512-cols of w1@w2)
//   [1024,1026)        c = b1@w2 + b2   (pad to 1056)
//   [1056,  +100000)   deg (int)
//   [101056,+200000)   g [N,2]  (unscaled x@W)
//   [301056,+200000)   acc (u64[N]; 301056*4 % 8 == 0)
constexpr int WS_W   = 0;
constexpr int WS_C   = 1024;
constexpr int WS_DEG = 1056;
constexpr int WS_G   = 101056;
constexpr int WS_ACC = 301056;

// ---- kernel 1: W = w1@w2, c = b1@w2+b2, deg = 1, acc = 0 ----
__global__ void k_prep(const float* __restrict__ w1, const float* __restrict__ w2,
                       const float* __restrict__ b1, const float* __restrict__ b2,
                       float* __restrict__ ws) {
    int i = blockIdx.x * blockDim.x + threadIdx.x;
    if (i < N_NODES) {
        reinterpret_cast<int*>(ws + WS_DEG)[i] = 1;                 // self-loop
        reinterpret_cast<unsigned long long*>(ws + WS_ACC)[i] = 0ull;
    }
    if (i < N_FEAT) {
        float a0 = 0.f, a1 = 0.f;
        for (int m = 0; m < 128; ++m) {
            float w = w1[i * 128 + m];
            a0 += w * w2[m * 2 + 0];
            a1 += w * w2[m * 2 + 1];
        }
        ws[WS_W + i] = a0;
        ws[WS_W + 512 + i] = a1;
        if (i < 2) {
            float s = b2[i];
            for (int m = 0; m < 128; ++m) s += b1[m] * w2[m * 2 + i];
            ws[WS_C + i] = s;
        }
    }
}

// ---- kernel 2 (fused): blocks %3==2 -> edge histogram; else rowdot g = x@W ----
// grid must be a multiple of 3.
__global__ __launch_bounds__(256) void k_fused(
    const float* __restrict__ x, const float* __restrict__ ws,
    const int* __restrict__ dst, int* __restrict__ deg, float2* __restrict__ g) {
    int b = blockIdx.x;
    if (b % 3 == 2) {
        // --- degree histogram, grid-stride over edges ---
        int nthr = (gridDim.x / 3) * 256;
        int tid  = (b / 3) * 256 + threadIdx.x;
        for (int e = tid; e < N_EDGES; e += nthr)
            atomicAdd(&deg[dst[e]], 1);
        return;
    }
    // --- rowdot: 2 rows per wave-iteration ---
    int rb = (b / 3) * 2 + (b % 3);                  // row-block index [0, 2*G/3)
    int nrb = (gridDim.x / 3) * 2;
    const vfloat4* W0q = reinterpret_cast<const vfloat4*>(ws + WS_W);
    const vfloat4* W1q = reinterpret_cast<const vfloat4*>(ws + WS_W + 512);
    int lane = threadIdx.x & 63;
    int wave = threadIdx.x >> 6;

    vfloat4 w0a = W0q[lane], w0b = W0q[64 + lane];
    vfloat4 w1a = W1q[lane], w1b = W1q[64 + lane];

    int wid = rb * 4 + wave;
    int nw  = nrb * 4;
    constexpr int NPAIR = N_NODES / 2;               // 50000 (N even)
    for (int p = wid; p < NPAIR; p += nw) {
        int row0 = p * 2;
        const vfloat4* xq0 = reinterpret_cast<const vfloat4*>(x + (size_t)row0 * N_FEAT);
        const vfloat4* xq1 = xq0 + 128;
        vfloat4 xa = __builtin_nontemporal_load(&xq0[lane]);
        vfloat4 xb = __builtin_nontemporal_load(&xq0[64 + lane]);
        vfloat4 ya = __builtin_nontemporal_load(&xq1[lane]);
        vfloat4 yb = __builtin_nontemporal_load(&xq1[64 + lane]);
        float a0 = xa.x*w0a.x + xa.y*w0a.y + xa.z*w0a.z + xa.w*w0a.w
                 + xb.x*w0b.x + xb.y*w0b.y + xb.z*w0b.z + xb.w*w0b.w;
        float a1 = xa.x*w1a.x + xa.y*w1a.y + xa.z*w1a.z + xa.w*w1a.w
                 + xb.x*w1b.x + xb.y*w1b.y + xb.z*w1b.z + xb.w*w1b.w;
        float b0 = ya.x*w0a.x + ya.y*w0a.y + ya.z*w0a.z + ya.w*w0a.w
                 + yb.x*w0b.x + yb.y*w0b.y + yb.z*w0b.z + yb.w*w0b.w;
        float b1v= ya.x*w1a.x + ya.y*w1a.y + ya.z*w1a.z + ya.w*w1a.w
                 + yb.x*w1b.x + yb.y*w1b.y + yb.z*w1b.z + yb.w*w1b.w;
        #pragma unroll
        for (int off = 32; off >= 1; off >>= 1) {
            a0 += __shfl_down(a0, off);
            a1 += __shfl_down(a1, off);
            b0 += __shfl_down(b0, off);
            b1v+= __shfl_down(b1v, off);
        }
        if (lane == 0) {
            g[row0]     = make_float2(a0, a1);
            g[row0 + 1] = make_float2(b0, b1v);
        }
    }
}

// ---- kernel 3: one u64 atomic per edge; dinv[src] computed on the fly ----
// acc[d] += pack( rn((g0[s]*dinv[s]+FXB)*FXS), rn((g1[s]*dinv[s]+FXB)*FXS) )
// 2 edges per thread for ILP.
__global__ void k_scatter64(const int* __restrict__ src, const int* __restrict__ dst,
                            const float2* __restrict__ g, const int* __restrict__ deg,
                            unsigned long long* __restrict__ acc) {
    constexpr int HALF = N_EDGES / 2;                // 800000
    int tid = blockIdx.x * blockDim.x + threadIdx.x;
    if (tid >= HALF) return;
    int e0 = tid, e1 = tid + HALF;
    int s0 = src[e0], d0 = dst[e0];
    int s1 = src[e1], d1 = dst[e1];
    float2 g0 = g[s0];
    float2 g1 = g[s1];
    float di0 = rsqrtf((float)deg[s0]);
    float di1 = rsqrtf((float)deg[s1]);
    unsigned int lo0 = (unsigned int)__float2int_rn((g0.x * di0 + FXB) * FXS);
    unsigned int hi0 = (unsigned int)__float2int_rn((g0.y * di0 + FXB) * FXS);
    unsigned int lo1 = (unsigned int)__float2int_rn((g1.x * di1 + FXB) * FXS);
    unsigned int hi1 = (unsigned int)__float2int_rn((g1.y * di1 + FXB) * FXS);
    atomicAdd(&acc[d0], ((unsigned long long)hi0 << 32) | (unsigned long long)lo0);
    atomicAdd(&acc[d1], ((unsigned long long)hi1 << 32) | (unsigned long long)lo1);
}

// ---- kernel 4: decode, unbias, add self-loop + bias ----
__global__ void k_final(const unsigned long long* __restrict__ acc,
                        const int* __restrict__ deg, const float2* __restrict__ g,
                        const float* __restrict__ cvec, float2* __restrict__ out) {
    int i = blockIdx.x * blockDim.x + threadIdx.x;
    if (i >= N_NODES) return;
    unsigned long long a = acc[i];
    long long lo = (long long)(a & 0xFFFFFFFFull);
    long long hi = (long long)(a >> 32);
    long long cnt = (long long)(deg[i] - 1);         // real in-edges
    long long bias = cnt << 25;                       // exact: cnt * FXB*FXS
    float di = rsqrtf((float)deg[i]);
    float2 gv = g[i];
    float s0 = (float)(lo - bias) * (1.0f / FXS) + gv.x * di;  // + self-loop (gs)
    float s1 = (float)(hi - bias) * (1.0f / FXS) + gv.y * di;
    out[i] = make_float2(di * s0 + cvec[0], di * s1 + cvec[1]);
}

extern "C" void kernel_launch(void* const* d_in, const int* in_sizes, int n_in,
                              void* d_out, int out_size, void* d_ws, size_t ws_size,
                              hipStream_t stream) {
    const float* x  = (const float*)d_in[0];
    const float* w1 = (const float*)d_in[1];
    const float* b1 = (const float*)d_in[2];
    const float* w2 = (const float*)d_in[3];
    const float* b2 = (const float*)d_in[4];
    const int*   ei = (const int*)d_in[5];   // [2, E]: src row then dst row
    const int* e_src = ei;
    const int* e_dst = ei + N_EDGES;
    float* ws  = (float*)d_ws;

    int*    deg = (int*)(ws + WS_DEG);
    float2* g   = (float2*)(ws + WS_G);
    unsigned long long* acc = (unsigned long long*)(ws + WS_ACC);

    constexpr int NB = (N_NODES + 255) / 256;        // 391
    constexpr int SB = (N_EDGES / 2 + 255) / 256;    // 3125

    k_prep<<<NB, 256, 0, stream>>>(w1, w2, b1, b2, ws);
    k_fused<<<3072, 256, 0, stream>>>(x, ws, e_dst, deg, g);
    k_scatter64<<<SB, 256, 0, stream>>>(e_src, e_dst, g, deg, acc);
    k_final<<<NB, 256, 0, stream>>>(acc, deg, g, ws + WS_C, (float2*)d_out);
}

// Round 5
// 90.665 us; speedup vs baseline: 3.0772x; 1.8094x over previous
//
#include <hip/hip_runtime.h>

constexpr int N_NODES = 100000;
constexpr int N_FEAT  = 512;    // 128 float4 per row
constexpr int N_EDGES = 1600000;

// fixed-point packing for LDS u64 accumulation
constexpr float FXS = 1048576.0f;  // 2^20 scale
constexpr float FXB = 32.0f;       // positivity bias; FXB*FXS = 2^25 (exact)

// binning
constexpr int BSH   = 8;                                  // 256 nodes per bin
constexpr int BINW  = 1 << BSH;                           // 256
constexpr int NBINS = (N_NODES + BINW - 1) >> BSH;        // 391
constexpr int BCAP  = 5120;   // slots/bin; mean 4092, sigma~64 -> +16 sigma
constexpr int NBB   = 128;    // binning blocks in k_fused
constexpr int CHUNK = N_EDGES / NBB;                      // 12500
constexpr int NRB   = 2048;   // rowdot blocks in k_fused

typedef float vfloat4 __attribute__((ext_vector_type(4)));

// ws float offsets
constexpr int WS_W    = 0;                    // [0,1024) two cols of w1@w2
constexpr int WS_C    = 1024;                 // c = b1@w2+b2 (pad to 1056)
constexpr int WS_CUR  = 1056;                 // bin cursors, NBINS ints (pad 512)
constexpr int WS_DEG  = WS_CUR + 512;         // 1568: deg[N] (int)
constexpr int WS_DINV = WS_DEG + N_NODES;     // 101568: dinv[N] (float)
constexpr int WS_G    = WS_DINV + N_NODES;    // 201568: g[N,2] (806272 % 8 == 0)
constexpr int WS_BINS = WS_G + 2 * N_NODES;   // 401568: bins u32[NBINS*BCAP] ~8 MB

// ---- kernel 1: W = w1@w2, c = b1@w2+b2, zero bin cursors ----
__global__ void k_prep(const float* __restrict__ w1, const float* __restrict__ w2,
                       const float* __restrict__ b1, const float* __restrict__ b2,
                       float* __restrict__ ws) {
    int i = blockIdx.x * blockDim.x + threadIdx.x;
    if (i < NBINS) reinterpret_cast<int*>(ws + WS_CUR)[i] = 0;
    if (i < N_FEAT) {
        float a0 = 0.f, a1 = 0.f;
        for (int m = 0; m < 128; ++m) {
            float w = w1[i * 128 + m];
            a0 += w * w2[m * 2 + 0];
            a1 += w * w2[m * 2 + 1];
        }
        ws[WS_W + i] = a0;
        ws[WS_W + 512 + i] = a1;
        if (i < 2) {
            float s = b2[i];
            for (int m = 0; m < 128; ++m) s += b1[m] * w2[m * 2 + i];
            ws[WS_C + i] = s;
        }
    }
}

// ---- kernel 2 (fused): blocks [0,NBB) bin edges by dst; rest do rowdot ----
__global__ __launch_bounds__(256) void k_fused(
    const float* __restrict__ x, float* __restrict__ ws,
    const int* __restrict__ src, const int* __restrict__ dst,
    float2* __restrict__ g) {
    int b = blockIdx.x;
    if (b < NBB) {
        // --- binning: count -> reserve -> place; edge packed into one u32 ---
        __shared__ int cnt[NBINS];
        __shared__ int offs[NBINS];
        __shared__ int cur2[NBINS];
        int tid = threadIdx.x;
        for (int i = tid; i < NBINS; i += 256) { cnt[i] = 0; cur2[i] = 0; }
        __syncthreads();
        int base = b * CHUNK;
        for (int e = base + tid; e < base + CHUNK; e += 256)
            atomicAdd(&cnt[dst[e] >> BSH], 1);
        __syncthreads();
        int* gcur = reinterpret_cast<int*>(ws + WS_CUR);
        for (int i = tid; i < NBINS; i += 256) {
            int c = cnt[i];
            int pos = c ? atomicAdd(&gcur[i], c) : 0;
            offs[i] = i * BCAP + pos;
        }
        __syncthreads();
        unsigned int* bins = reinterpret_cast<unsigned int*>(ws + WS_BINS);
        for (int e = base + tid; e < base + CHUNK; e += 256) {
            int d = dst[e], s = src[e];
            int bin = d >> BSH;
            int r = atomicAdd(&cur2[bin], 1);
            bins[offs[bin] + r] = (unsigned int)s | ((unsigned int)(d & (BINW - 1)) << 17);
        }
        return;
    }
    // --- rowdot: g = x @ W, 2 rows per wave-iteration ---
    int rb = b - NBB;
    const vfloat4* W0q = reinterpret_cast<const vfloat4*>(ws + WS_W);
    const vfloat4* W1q = reinterpret_cast<const vfloat4*>(ws + WS_W + 512);
    int lane = threadIdx.x & 63;
    int wave = threadIdx.x >> 6;

    vfloat4 w0a = W0q[lane], w0b = W0q[64 + lane];
    vfloat4 w1a = W1q[lane], w1b = W1q[64 + lane];

    int wid = rb * 4 + wave;
    int nw  = NRB * 4;
    constexpr int NPAIR = N_NODES / 2;               // 50000
    for (int p = wid; p < NPAIR; p += nw) {
        int row0 = p * 2;
        const vfloat4* xq0 = reinterpret_cast<const vfloat4*>(x + (size_t)row0 * N_FEAT);
        const vfloat4* xq1 = xq0 + 128;
        vfloat4 xa = __builtin_nontemporal_load(&xq0[lane]);
        vfloat4 xb = __builtin_nontemporal_load(&xq0[64 + lane]);
        vfloat4 ya = __builtin_nontemporal_load(&xq1[lane]);
        vfloat4 yb = __builtin_nontemporal_load(&xq1[64 + lane]);
        float a0 = xa.x*w0a.x + xa.y*w0a.y + xa.z*w0a.z + xa.w*w0a.w
                 + xb.x*w0b.x + xb.y*w0b.y + xb.z*w0b.z + xb.w*w0b.w;
        float a1 = xa.x*w1a.x + xa.y*w1a.y + xa.z*w1a.z + xa.w*w1a.w
                 + xb.x*w1b.x + xb.y*w1b.y + xb.z*w1b.z + xb.w*w1b.w;
        float b0 = ya.x*w0a.x + ya.y*w0a.y + ya.z*w0a.z + ya.w*w0a.w
                 + yb.x*w0b.x + yb.y*w0b.y + yb.z*w0b.z + yb.w*w0b.w;
        float b1v= ya.x*w1a.x + ya.y*w1a.y + ya.z*w1a.z + ya.w*w1a.w
                 + yb.x*w1b.x + yb.y*w1b.y + yb.z*w1b.z + yb.w*w1b.w;
        #pragma unroll
        for (int off = 32; off >= 1; off >>= 1) {
            a0 += __shfl_down(a0, off);
            a1 += __shfl_down(a1, off);
            b0 += __shfl_down(b0, off);
            b1v+= __shfl_down(b1v, off);
        }
        if (lane == 0) {
            g[row0]     = make_float2(a0, a1);
            g[row0 + 1] = make_float2(b0, b1v);
        }
    }
}

// ---- kernel 3: per-bin degree count (no global atomics); deg & dinv ----
__global__ __launch_bounds__(256) void k_deg(float* __restrict__ ws) {
    int b = blockIdx.x;
    const int* gcur = reinterpret_cast<const int*>(ws + WS_CUR);
    const unsigned int* bins = reinterpret_cast<const unsigned int*>(ws + WS_BINS) + b * BCAP;
    int n = min(gcur[b], BCAP);
    __shared__ int cnt[BINW];
    cnt[threadIdx.x] = 0;
    __syncthreads();
    for (int i = threadIdx.x; i < n; i += 256)
        atomicAdd(&cnt[bins[i] >> 17], 1);
    __syncthreads();
    int d = (b << BSH) + threadIdx.x;
    if (d < N_NODES) {
        int dg = cnt[threadIdx.x] + 1;               // + self-loop
        reinterpret_cast<int*>(ws + WS_DEG)[d] = dg;
        ws[WS_DINV + d] = rsqrtf((float)dg);
    }
}

// ---- kernel 4: per-bin value accumulation in LDS fixed-point; finalize ----
__global__ __launch_bounds__(256) void k_pass2(float* __restrict__ ws,
                                               float2* __restrict__ out) {
    int b = blockIdx.x;
    const int* gcur = reinterpret_cast<const int*>(ws + WS_CUR);
    const unsigned int* bins = reinterpret_cast<const unsigned int*>(ws + WS_BINS) + b * BCAP;
    const int* deg = reinterpret_cast<const int*>(ws + WS_DEG);
    const float* dinv = ws + WS_DINV;
    const float2* g = reinterpret_cast<const float2*>(ws + WS_G);
    int n = min(gcur[b], BCAP);
    __shared__ unsigned long long acc[BINW];
    acc[threadIdx.x] = 0ull;
    __syncthreads();
    for (int i = threadIdx.x; i < n; i += 256) {
        unsigned int p = bins[i];
        int s  = (int)(p & 0x1FFFFu);
        int ld = (int)(p >> 17);
        float2 gv = g[s];
        float di = dinv[s];
        unsigned int lo = (unsigned int)__float2int_rn((gv.x * di + FXB) * FXS);
        unsigned int hi = (unsigned int)__float2int_rn((gv.y * di + FXB) * FXS);
        atomicAdd(&acc[ld], ((unsigned long long)hi << 32) | (unsigned long long)lo);
    }
    __syncthreads();
    int d = (b << BSH) + threadIdx.x;
    if (d < N_NODES) {
        unsigned long long a = acc[threadIdx.x];
        long long cnt = (long long)(deg[d] - 1);
        long long bias = cnt << 25;                   // exact: cnt * FXB*FXS
        long long lo = (long long)(a & 0xFFFFFFFFull) - bias;
        long long hi = (long long)(a >> 32) - bias;
        float di = dinv[d];
        float2 gv = g[d];
        float s0 = (float)lo * (1.0f / FXS) + gv.x * di;   // + self-loop term
        float s1 = (float)hi * (1.0f / FXS) + gv.y * di;
        out[d] = make_float2(di * s0 + ws[WS_C + 0], di * s1 + ws[WS_C + 1]);
    }
}

extern "C" void kernel_launch(void* const* d_in, const int* in_sizes, int n_in,
                              void* d_out, int out_size, void* d_ws, size_t ws_size,
                              hipStream_t stream) {
    const float* x  = (const float*)d_in[0];
    const float* w1 = (const float*)d_in[1];
    const float* b1 = (const float*)d_in[2];
    const float* w2 = (const float*)d_in[3];
    const float* b2 = (const float*)d_in[4];
    const int*   ei = (const int*)d_in[5];   // [2, E]: src row then dst row
    float* ws = (float*)d_ws;

    float2* g = (float2*)(ws + WS_G);

    k_prep<<<2, 256, 0, stream>>>(w1, w2, b1, b2, ws);
    k_fused<<<NBB + NRB, 256, 0, stream>>>(x, ws, ei, ei + N_EDGES, g);
    k_deg<<<NBINS, 256, 0, stream>>>(ws);
    k_pass2<<<NBINS, 256, 0, stream>>>(ws, (float2*)d_out);
}